// Round 2
// baseline (94.415 us; speedup 1.0000x reference)
//
#include <hip/hip_runtime.h>

// SimplifiedMambaBlock: the scan is h = A_t * h with h0 = 0 and no input
// injection, so h == 0 forever, ssm_out == 0, y == 0, and
// out = out_proj(0) + residual == x bit-exactly. The optimal kernel is a
// copy of x -> out.
//
// R1 post-mortem: hipMemcpyAsync captured as a graph memcpy node -> SDMA
// engine at ~0.73 TB/s (92 us). A shader copy hits ~6 TB/s (the harness's
// own fill kernels measure 6.1 TB/s). So: hand-rolled float4 copy kernel.
// 8*2048*512 floats = 2,097,152 float4 -> 8192 blocks x 256 threads.

__global__ __launch_bounds__(256) void copy_f4(const float4* __restrict__ src,
                                               float4* __restrict__ dst) {
    int i = blockIdx.x * blockDim.x + threadIdx.x;
    dst[i] = src[i];
}

extern "C" void kernel_launch(void* const* d_in, const int* in_sizes, int n_in,
                              void* d_out, int out_size, void* d_ws, size_t ws_size,
                              hipStream_t stream) {
    const float4* x = (const float4*)d_in[0];   // (8,2048,512) fp32, 16B-aligned
    float4* out = (float4*)d_out;
    int n4 = out_size / 4;                      // 2,097,152 — divisible by 4*256
    copy_f4<<<n4 / 256, 256, 0, stream>>>(x, out);
}